// Round 1
// baseline (20.289 us; speedup 1.0000x reference)
//
#include <hip/hip_runtime.h>

// Shapley fusion: L=5 views, C=64 channels, N=128*256 spatial positions.
// Key simplification: f(subset) = relu(b + sum_{l in subset} d[l]) where
// d[l] = dot(feats[l,:,n], w)  -- the subset GEMM collapses to 5 dots.
// Shapley coef for L=5: wt[|m|] = {-, -0.6, 0.05, 1/30, 0.05, 0.2}
// (singleton carries the -(L-2)/L correction; |m|>=2 uses (t-1)!(L-t)!/L!).

constexpr int L_VIEWS = 5;
constexpr int C_CH    = 64;
constexpr int NPIX    = 128 * 256;   // 32768

__global__ __launch_bounds__(64)
void shapley_fusion_kernel(const float* __restrict__ feats,
                           const float* __restrict__ w,
                           const float* __restrict__ bptr,
                           float* __restrict__ out)
{
    // One wave per block. Lane layout: lane = n4_local (0..15) + 16*cgroup (0..3).
    // Block covers 64 consecutive n (16 float4 groups); each thread owns 16 channels.
    const int lane = threadIdx.x;
    const int n4l  = lane & 15;
    const int cg   = lane >> 4;
    const int n    = blockIdx.x * 64 + n4l * 4;
    const int c0   = cg * 16;

    // Load this thread's 16-channel slice of w (contiguous, float4).
    float wreg[16];
#pragma unroll
    for (int i = 0; i < 4; ++i) {
        const float4 wv = *reinterpret_cast<const float4*>(w + c0 + i * 4);
        wreg[i * 4 + 0] = wv.x; wreg[i * 4 + 1] = wv.y;
        wreg[i * 4 + 2] = wv.z; wreg[i * 4 + 3] = wv.w;
    }
    const float bias = bptr[0];

    // Phase A: partial dots d[l][j] over this thread's channels, j = n sub-index.
    float d[L_VIEWS][4];
#pragma unroll
    for (int l = 0; l < L_VIEWS; ++l)
#pragma unroll
        for (int j = 0; j < 4; ++j) d[l][j] = 0.f;

#pragma unroll
    for (int l = 0; l < L_VIEWS; ++l) {
#pragma unroll
        for (int cc = 0; cc < 16; ++cc) {
            const float4 v = *reinterpret_cast<const float4*>(
                feats + ((size_t)(l * C_CH + c0 + cc) * NPIX + n));
            d[l][0] += v.x * wreg[cc];
            d[l][1] += v.y * wreg[cc];
            d[l][2] += v.z * wreg[cc];
            d[l][3] += v.w * wreg[cc];
        }
    }

    // Reduce partial dots across the 4 c-groups (lanes xor 16, xor 32).
#pragma unroll
    for (int l = 0; l < L_VIEWS; ++l) {
#pragma unroll
        for (int j = 0; j < 4; ++j) {
            d[l][j] += __shfl_xor(d[l][j], 16, 64);
            d[l][j] += __shfl_xor(d[l][j], 32, 64);
        }
    }

    // Phase B: subset lattice -> shapley -> softmax, per n sub-index.
    // Fully unrolled: all array indices compile-time (stays in VGPRs).
    constexpr float WT1 = -0.6f;          // singleton: -(L-2)/L
    constexpr float WT2 = 0.05f;          // 1!*3!/5!
    constexpr float WT3 = 1.0f / 30.0f;   // 2!*2!/5!
    constexpr float WT4 = 0.05f;          // 3!*1!/5!
    constexpr float WT5 = 0.2f;           // 4!*0!/5!

    float attn[L_VIEWS][4];
#pragma unroll
    for (int j = 0; j < 4; ++j) {
        float s[32];
        s[0] = 0.f;
        float sh[L_VIEWS] = {0.f, 0.f, 0.f, 0.f, 0.f};
#pragma unroll
        for (int m = 1; m < 32; ++m) {
            const int lb  = m & (-m);
            const int lbi = __builtin_ctz(m);
            s[m] = s[m ^ lb] + d[lbi][j];
            const float f = fmaxf(s[m] + bias, 0.f);
            const int pc = __builtin_popcount(m);
            const float wt = (pc == 1) ? WT1 : (pc == 2) ? WT2
                           : (pc == 3) ? WT3 : (pc == 4) ? WT4 : WT5;
#pragma unroll
            for (int i = 0; i < L_VIEWS; ++i)
                if (m & (1 << i)) sh[i] += wt * f;
        }
        // softmax over the 5 views
        float mx = sh[0];
#pragma unroll
        for (int i = 1; i < L_VIEWS; ++i) mx = fmaxf(mx, sh[i]);
        float e[L_VIEWS];
        float sum = 0.f;
#pragma unroll
        for (int i = 0; i < L_VIEWS; ++i) { e[i] = __expf(sh[i] - mx); sum += e[i]; }
        const float inv = 1.f / sum;
#pragma unroll
        for (int i = 0; i < L_VIEWS; ++i) attn[i][j] = e[i] * inv;
    }

    // Phase C: fused output for this thread's 16 channels x 4 n.
    // Re-reads feats just loaded by this block -> L1/L2 hits.
#pragma unroll
    for (int cc = 0; cc < 16; ++cc) {
        const int c = c0 + cc;
        float4 acc = {0.f, 0.f, 0.f, 0.f};
#pragma unroll
        for (int l = 0; l < L_VIEWS; ++l) {
            const float4 v = *reinterpret_cast<const float4*>(
                feats + ((size_t)(l * C_CH + c) * NPIX + n));
            acc.x += v.x * attn[l][0];
            acc.y += v.y * attn[l][1];
            acc.z += v.z * attn[l][2];
            acc.w += v.w * attn[l][3];
        }
        *reinterpret_cast<float4*>(out + (size_t)c * NPIX + n) = acc;
    }
}

extern "C" void kernel_launch(void* const* d_in, const int* in_sizes, int n_in,
                              void* d_out, int out_size, void* d_ws, size_t ws_size,
                              hipStream_t stream) {
    const float* feats = (const float*)d_in[0];   // [5,64,128,256] fp32
    const float* w     = (const float*)d_in[1];   // [64,1] fp32
    const float* b     = (const float*)d_in[2];   // [1] fp32
    float* out         = (float*)d_out;           // [64,128,256] fp32

    // 512 blocks x 64 threads: each block handles 64 consecutive n.
    shapley_fusion_kernel<<<NPIX / 64, 64, 0, stream>>>(feats, w, b, out);
}

// Round 2
// 16.696 us; speedup vs baseline: 1.2152x; 1.2152x over previous
//
#include <hip/hip_runtime.h>

// Shapley fusion: L=5 views, C=64 channels, N=128*256 spatial positions.
// f(subset) = relu(b + sum_{l in subset} d[l]) where d[l] = dot(feats[l,:,n], w)
// -- the reference's [M,N,C] subset GEMM collapses to 5 dots per pixel.
// Shapley coef for L=5 by subset size: {-, -0.6, 0.05, 1/30, 0.05, 0.2}.
//
// Geometry (round-2): 2048 waves (2/SIMD, all 1024 SIMDs busy).
// Per wave: 16 consecutive n. Lane = n4l(0..3) + 4*cg(0..15); each thread
// owns 4 channels x 4 n. The wave's full feats slice (5 x 4ch x float4 =
// 80 VGPR/thread) lives in registers -> feats is read from HBM exactly once;
// phase C consumes registers instead of re-reading L2.

constexpr int L_VIEWS = 5;
constexpr int C_CH    = 64;
constexpr int NPIX    = 128 * 256;   // 32768

__global__ __launch_bounds__(256)
void shapley_fusion_kernel(const float* __restrict__ feats,
                           const float* __restrict__ w,
                           const float* __restrict__ bptr,
                           float* __restrict__ out)
{
    const int lane = threadIdx.x & 63;
    const int wid  = threadIdx.x >> 6;       // wave in block (0..3)
    const int n4l  = lane & 3;               // n quad within wave
    const int cg   = lane >> 2;              // channel group (0..15)
    const int n    = (blockIdx.x * 4 + wid) * 16 + n4l * 4;
    const int c0   = cg * 4;

    const float4 wv  = *reinterpret_cast<const float4*>(w + c0);
    const float bias = bptr[0];

    // Phase A: load the thread's entire feats slice into registers.
    // 20 float4 loads issued back-to-back -> deep VMEM queue, BW-saturating.
    float4 v[L_VIEWS][4];
#pragma unroll
    for (int l = 0; l < L_VIEWS; ++l)
#pragma unroll
        for (int cc = 0; cc < 4; ++cc)
            v[l][cc] = *reinterpret_cast<const float4*>(
                feats + ((size_t)(l * C_CH + c0 + cc) * NPIX + n));

    // Partial dots over this thread's 4 channels, per n sub-index j.
    float d[L_VIEWS][4];
#pragma unroll
    for (int l = 0; l < L_VIEWS; ++l) {
        d[l][0] = v[l][0].x * wv.x + v[l][1].x * wv.y + v[l][2].x * wv.z + v[l][3].x * wv.w;
        d[l][1] = v[l][0].y * wv.x + v[l][1].y * wv.y + v[l][2].y * wv.z + v[l][3].y * wv.w;
        d[l][2] = v[l][0].z * wv.x + v[l][1].z * wv.y + v[l][2].z * wv.z + v[l][3].z * wv.w;
        d[l][3] = v[l][0].w * wv.x + v[l][1].w * wv.y + v[l][2].w * wv.z + v[l][3].w * wv.w;
    }

    // Butterfly reduce across the 16 channel-groups (lane bits 2..5).
#pragma unroll
    for (int l = 0; l < L_VIEWS; ++l) {
#pragma unroll
        for (int j = 0; j < 4; ++j) {
            d[l][j] += __shfl_xor(d[l][j], 4, 64);
            d[l][j] += __shfl_xor(d[l][j], 8, 64);
            d[l][j] += __shfl_xor(d[l][j], 16, 64);
            d[l][j] += __shfl_xor(d[l][j], 32, 64);
        }
    }

    // Phase B: subset lattice -> shapley -> softmax, per n sub-index.
    // Fully unrolled: all indices compile-time (stays in VGPRs).
    constexpr float WT1 = -0.6f;          // singleton: -(L-2)/L
    constexpr float WT2 = 0.05f;          // 1!*3!/5!
    constexpr float WT3 = 1.0f / 30.0f;   // 2!*2!/5!
    constexpr float WT4 = 0.05f;          // 3!*1!/5!
    constexpr float WT5 = 0.2f;           // 4!*0!/5!

    float attn[L_VIEWS][4];
#pragma unroll
    for (int j = 0; j < 4; ++j) {
        float s[32];
        s[0] = 0.f;
        float sh[L_VIEWS] = {0.f, 0.f, 0.f, 0.f, 0.f};
#pragma unroll
        for (int m = 1; m < 32; ++m) {
            const int lb  = m & (-m);
            const int lbi = __builtin_ctz(m);
            s[m] = s[m ^ lb] + d[lbi][j];
            const float f = fmaxf(s[m] + bias, 0.f);
            const int pc = __builtin_popcount(m);
            const float wt = (pc == 1) ? WT1 : (pc == 2) ? WT2
                           : (pc == 3) ? WT3 : (pc == 4) ? WT4 : WT5;
#pragma unroll
            for (int i = 0; i < L_VIEWS; ++i)
                if (m & (1 << i)) sh[i] += wt * f;
        }
        float mx = sh[0];
#pragma unroll
        for (int i = 1; i < L_VIEWS; ++i) mx = fmaxf(mx, sh[i]);
        float e[L_VIEWS];
        float sum = 0.f;
#pragma unroll
        for (int i = 0; i < L_VIEWS; ++i) { e[i] = __expf(sh[i] - mx); sum += e[i]; }
        const float inv = 1.f / sum;
#pragma unroll
        for (int i = 0; i < L_VIEWS; ++i) attn[i][j] = e[i] * inv;
    }

    // Phase C: fused output straight from registers -- no feats re-read.
#pragma unroll
    for (int cc = 0; cc < 4; ++cc) {
        float4 acc;
        acc.x = v[0][cc].x * attn[0][0];
        acc.y = v[0][cc].y * attn[0][1];
        acc.z = v[0][cc].z * attn[0][2];
        acc.w = v[0][cc].w * attn[0][3];
#pragma unroll
        for (int l = 1; l < L_VIEWS; ++l) {
            acc.x += v[l][cc].x * attn[l][0];
            acc.y += v[l][cc].y * attn[l][1];
            acc.z += v[l][cc].z * attn[l][2];
            acc.w += v[l][cc].w * attn[l][3];
        }
        *reinterpret_cast<float4*>(out + (size_t)(c0 + cc) * NPIX + n) = acc;
    }
}

extern "C" void kernel_launch(void* const* d_in, const int* in_sizes, int n_in,
                              void* d_out, int out_size, void* d_ws, size_t ws_size,
                              hipStream_t stream) {
    const float* feats = (const float*)d_in[0];   // [5,64,128,256] fp32
    const float* w     = (const float*)d_in[1];   // [64,1] fp32
    const float* b     = (const float*)d_in[2];   // [1] fp32
    float* out         = (float*)d_out;           // [64,128,256] fp32

    // 512 blocks x 256 threads = 2048 waves; each wave owns 16 consecutive n.
    shapley_fusion_kernel<<<NPIX / 64, 256, 0, stream>>>(feats, w, b, out);
}